// Round 7
// baseline (181.396 us; speedup 1.0000x reference)
//
#include <hip/hip_runtime.h>
#include <hip/hip_bf16.h>

#define NN  4
#define CIN 96
#define C1  128
#define C2  144
#define HH  128
#define WW  256
#define NPX ((size_t)NN * HH * WW)          // pixels per chunk-plane (131072)

typedef short bf16x8 __attribute__((ext_vector_type(8)));
typedef float f32x4  __attribute__((ext_vector_type(4)));
typedef unsigned int u32x4 __attribute__((ext_vector_type(4)));

__device__ __forceinline__ short f2bs(float v) {
    __hip_bfloat16 b = __float2bfloat16(v);
    short s; __builtin_memcpy(&s, &b, 2); return s;
}

// async global->LDS, 16B per lane. LDS dest linear (base + lane*16).
__device__ __forceinline__ void gld16(const void* g, void* l) {
    __builtin_amdgcn_global_load_lds(
        (const __attribute__((address_space(1))) void*)g,
        (__attribute__((address_space(3))) void*)l, 16, 0, 0);
}

// ---------------------------------------------------------------------------
// NCHW fp32 -> chunk-major bf16: featT[kc][n][h][w][32], kc = ci>>5.
__global__ __launch_bounds__(256) void transpose_feat(
    const float* __restrict__ feat, short* __restrict__ featT,
    short* __restrict__ zbuf)
{
    __shared__ unsigned int lds[48 * 258];        // 49.5 KB
    const int tid = threadIdx.x;
    const int h = blockIdx.x & (HH - 1);
    const int n = blockIdx.x >> 7;

    if (blockIdx.x == 0 && tid < 32) zbuf[tid] = 0;

    #pragma unroll 4
    for (int cp = 0; cp < 48; ++cp) {             // channel pairs
        float v0 = feat[(((size_t)n * CIN + 2 * cp    ) * HH + h) * WW + tid];
        float v1 = feat[(((size_t)n * CIN + 2 * cp + 1) * HH + h) * WW + tid];
        unsigned int p = (unsigned int)(unsigned short)f2bs(v0)
                       | ((unsigned int)(unsigned short)f2bs(v1) << 16);
        lds[cp * 258 + tid] = p;
    }
    __syncthreads();
    const size_t rowbase = (size_t)(n * HH + h) * WW * 32;
    #pragma unroll
    for (int kc = 0; kc < 3; ++kc) {
        short* dst = featT + (size_t)kc * (NPX * 32) + rowbase;
        #pragma unroll
        for (int it = 0; it < 4; ++it) {
            const int slot = it * 256 + tid;
            const int px = slot >> 2, sub = slot & 3;
            u32x4 v;                               // ci pairs kc*16+sub*4+k
            #pragma unroll
            for (int k = 0; k < 4; ++k)
                v[k] = lds[(kc * 16 + sub * 4 + k) * 258 + px];
            *(u32x4*)&dst[(size_t)slot * 8] = v;
        }
    }
}

// ---------------------------------------------------------------------------
// Pack weights (co,ci,3,3) fp32 -> B-fragment-ordered bf16:
// wp[(((kci*9+tap)*nct + ct)*64 + lane)*8 + j], co=ct*16+col, ci=kci*32+quad*8+j
__global__ __launch_bounds__(256) void pack_wB(
    const float* __restrict__ w, short* __restrict__ wp,
    int cin, int nct, int total)
{
    int i = blockIdx.x * 256 + threadIdx.x;
    if (i >= total) return;
    const int j    = i & 7;
    const int col  = (i >> 3) & 15;
    const int quad = (i >> 7) & 3;
    int t = i >> 9;                               // (kci*9+tap)*nct + ct
    const int ct  = t % nct;  t /= nct;
    const int tap = t % 9;
    const int kci = t / 9;
    const int co = ct * 16 + col;
    const int ci = kci * 32 + quad * 8 + j;
    wp[i] = f2bs(w[((size_t)co * cin + ci) * 9 + tap]);
}

// ---------------------------------------------------------------------------
// conv1: 1-row blocks, 256 thr / 4 waves (wave = 64-px strip, mt=4), grid 512
// = 2 blocks/CU. A single-buffered (XOR-swizzled via source). B double-
// buffered PER TAP (8.2 KB each): stage tap q+1 -> buf^1, then compute tap q
// (pure LDS) -> the vmcnt(0) drain at the phase barrier lands after ~1.4k cyc
// of MFMA, hiding the B-stage latency while keeping 2 blocks/CU.
__global__ __launch_bounds__(256, 2) void conv1_mfma(
    const short* __restrict__ featT, const short* __restrict__ w1p,
    const float* __restrict__ b1, short* __restrict__ hfeat,
    const short* __restrict__ zbuf)
{
    __shared__ __attribute__((aligned(16))) short ldsA[3 * 258 * 32];   // 49,536 B
    __shared__ __attribute__((aligned(16))) short ldsB[2][8 * 512];     // 16,384 B
    const int tid  = threadIdx.x;
    const int bid  = ((blockIdx.x & 7) << 6) + (blockIdx.x >> 3); // 512 = 8x64
    const int h    = bid & (HH - 1);
    const int n    = bid >> 7;
    const int lane = tid & 63, wave = tid >> 6;
    const int quad = lane >> 4, col = lane & 15;
    const int wp0  = wave * 64;

    f32x4 acc[4][8];
    #pragma unroll
    for (int mt = 0; mt < 4; ++mt)
        #pragma unroll
        for (int ct = 0; ct < 8; ++ct)
            #pragma unroll
            for (int r = 0; r < 4; ++r) acc[mt][ct][r] = 0.f;

    auto stageA = [&](int kci) {
        const short* cbase = featT + (size_t)kci * (NPX * 32);
        for (int s = tid; s < 3 * 258 * 4; s += 256) {
            const int cig = s & 3;
            const int px  = (s >> 2) % 258;
            const int row = (s >> 2) / 258;
            const int hh = h + row - 1, gw = px - 1;
            const short* g = zbuf;
            if (hh >= 0 && hh < HH && gw >= 0 && gw < WW)
                g = cbase + ((size_t)(n * HH + hh) * WW + gw) * 32
                    + ((cig ^ ((px >> 1) & 3)) << 3);   // source pre-swizzle
            gld16(g, &ldsA[s * 8]);
        }
    };
    auto stageB = [&](int q, int pbuf) {          // q = kci*9+tap
        const short* gB = w1p + (((size_t)q * 8) << 9);
        #pragma unroll
        for (int t = 0; t < 2; ++t)               // 512 slots x 16B contiguous
            gld16(gB + (t * 256 + tid) * 8, &ldsB[pbuf][(t * 256 + tid) * 8]);
    };
    auto compute = [&](int tap, const short* Bbuf) {
        const int dh = tap / 3, dw = tap % 3;
        bf16x8 af[4];
        #pragma unroll
        for (int mt = 0; mt < 4; ++mt) {
            const int px = wp0 + mt * 16 + col + dw;
            const int slot = (dh * 258 + px) * 4 + (quad ^ ((px >> 1) & 3));
            af[mt] = *(const bf16x8*)&ldsA[slot * 8];
        }
        #pragma unroll
        for (int ct = 0; ct < 8; ++ct) {
            const bf16x8 bfr = *(const bf16x8*)&Bbuf[(ct << 9) + (lane << 3)];
            #pragma unroll
            for (int mt = 0; mt < 4; ++mt)
                acc[mt][ct] = __builtin_amdgcn_mfma_f32_16x16x32_bf16(af[mt], bfr, acc[mt][ct], 0, 0, 0);
        }
    };

    stageA(0);
    stageB(0, 0);
    __syncthreads();                              // prologue drain
    int p = 0;
    for (int kci = 0; kci < 3; ++kci) {
        if (kci) {                                // A restage (exposed; co-block covers)
            stageA(kci);
            __syncthreads();
        }
        for (int tap = 0; tap < 9; ++tap) {
            const int q = kci * 9 + tap;
            if (q < 26) stageB(q + 1, p ^ 1);     // prefetch next tap's B
            compute(tap, ldsB[p]);                // pure-LDS compute hides drain
            __syncthreads();
            p ^= 1;
        }
    }

    float bias[8];
    #pragma unroll
    for (int ct = 0; ct < 8; ++ct) bias[ct] = b1[ct * 16 + col];
    #pragma unroll
    for (int mt = 0; mt < 4; ++mt)
        #pragma unroll
        for (int r = 0; r < 4; ++r) {
            const int w = wp0 + mt * 16 + quad * 4 + r;
            const size_t pxw = (size_t)(n * HH + h) * WW + w;
            #pragma unroll
            for (int ct = 0; ct < 8; ++ct) {
                float a = acc[mt][ct][r] + bias[ct];
                a = a > 0.f ? a : 0.1f * a;       // LeakyReLU(0.1)
                hfeat[((size_t)(ct >> 1) * NPX + pxw) * 32 + (ct & 1) * 16 + col] = f2bs(a);
            }
        }
}

// ---------------------------------------------------------------------------
// conv2 + fused epilogue. Same per-tap B-dbuf structure (36 phases, nct=9).
// LDS 68 KB -> 2 blocks/CU. Epilogue: LDS out-stage (stride 1028) -> fully
// coalesced copy-out (keeps WRITE_SIZE at the 16.4 MB ideal).
__global__ __launch_bounds__(256, 2) void conv2_fused(
    const short* __restrict__ hfeat, const short* __restrict__ w2p,
    const float* __restrict__ b2, const float* __restrict__ flow,
    float* __restrict__ out, const short* __restrict__ zbuf)
{
    __shared__ __attribute__((aligned(16))) short ldsA[3 * 258 * 32];   // 49,536 B
    __shared__ __attribute__((aligned(16))) short ldsB[2][9 * 512];     // 18,432 B
    const int tid  = threadIdx.x;
    const int bid  = ((blockIdx.x & 7) << 6) + (blockIdx.x >> 3);
    const int h    = bid & (HH - 1);
    const int n    = bid >> 7;
    const int lane = tid & 63, wave = tid >> 6;
    const int quad = lane >> 4, col = lane & 15;
    const int wp0  = wave * 64;

    f32x4 acc[4][9];
    #pragma unroll
    for (int mt = 0; mt < 4; ++mt)
        #pragma unroll
        for (int ct = 0; ct < 9; ++ct)
            #pragma unroll
            for (int r = 0; r < 4; ++r) acc[mt][ct][r] = 0.f;

    auto stageA = [&](int kci) {
        const short* cbase = hfeat + (size_t)kci * (NPX * 32);
        for (int s = tid; s < 3 * 258 * 4; s += 256) {
            const int cig = s & 3;
            const int px  = (s >> 2) % 258;
            const int row = (s >> 2) / 258;
            const int hh = h + row - 1, gw = px - 1;
            const short* g = zbuf;
            if (hh >= 0 && hh < HH && gw >= 0 && gw < WW)
                g = cbase + ((size_t)(n * HH + hh) * WW + gw) * 32
                    + ((cig ^ ((px >> 1) & 3)) << 3);
            gld16(g, &ldsA[s * 8]);
        }
    };
    auto stageB = [&](int q, int pbuf) {          // q = kci*9+tap; 576 slots
        const short* gB = w2p + (((size_t)q * 9) << 9);
        for (int t = tid; t < 576; t += 256)
            gld16(gB + t * 8, &ldsB[pbuf][t * 8]);
    };
    auto compute = [&](int tap, const short* Bbuf) {
        const int dh = tap / 3, dw = tap % 3;
        bf16x8 af[4];
        #pragma unroll
        for (int mt = 0; mt < 4; ++mt) {
            const int px = wp0 + mt * 16 + col + dw;
            const int slot = (dh * 258 + px) * 4 + (quad ^ ((px >> 1) & 3));
            af[mt] = *(const bf16x8*)&ldsA[slot * 8];
        }
        #pragma unroll
        for (int ct = 0; ct < 9; ++ct) {
            const bf16x8 bfr = *(const bf16x8*)&Bbuf[(ct << 9) + (lane << 3)];
            #pragma unroll
            for (int mt = 0; mt < 4; ++mt)
                acc[mt][ct] = __builtin_amdgcn_mfma_f32_16x16x32_bf16(af[mt], bfr, acc[mt][ct], 0, 0, 0);
        }
    };

    stageA(0);
    stageB(0, 0);
    __syncthreads();
    int p = 0;
    for (int kci = 0; kci < 4; ++kci) {
        if (kci) {
            stageA(kci);
            __syncthreads();
        }
        for (int tap = 0; tap < 9; ++tap) {
            const int q = kci * 9 + tap;
            if (q < 35) stageB(q + 1, p ^ 1);
            compute(tap, ldsB[p]);
            __syncthreads();
            p ^= 1;
        }
    }

    // ---- epilogue: ldsA reused as out-stage [2][4][1028] + flow cache ----
    float* outs = (float*)ldsA;                   // 32,896 B
    float* flds = (float*)ldsA + 8224;            // [2][3][264], 6,336 B
    for (int i = tid; i < 2 * 3 * 258; i += 256) {
        const int px = i % 258;
        const int t  = i / 258;
        const int row = t % 3, c = t / 3;
        const int hh = h + row - 1, gw = px - 1;
        float v = 0.f;
        if (hh >= 0 && hh < HH && gw >= 0 && gw < WW)
            v = flow[(((size_t)n * 2 + c) * HH + hh) * WW + gw];
        flds[(c * 3 + row) * 264 + px] = v;
    }
    __syncthreads();

    const int a_ = col >> 2, b_ = col & 3;
    float bias[9];
    #pragma unroll
    for (int k = 0; k < 9; ++k) bias[k] = b2[k * 16 + col];

    #pragma unroll
    for (int mt = 0; mt < 4; ++mt) {
        const int w0 = wp0 + mt * 16 + quad * 4;
        float fw[2][3][6];                        // flow window w0-1 .. w0+4
        #pragma unroll
        for (int c = 0; c < 2; ++c)
            #pragma unroll
            for (int ki = 0; ki < 3; ++ki)
                #pragma unroll
                for (int j = 0; j < 6; ++j)
                    fw[c][ki][j] = flds[(c * 3 + ki) * 264 + w0 + j];
        #pragma unroll
        for (int r = 0; r < 4; ++r) {
            const int w = w0 + r;
            float v[9], mx = -1e30f;
            #pragma unroll
            for (int k = 0; k < 9; ++k) {
                v[k] = 0.25f * (acc[mt][k][r] + bias[k]);
                mx = fmaxf(mx, v[k]);
            }
            float s = 0.f;
            #pragma unroll
            for (int k = 0; k < 9; ++k) { v[k] = __expf(v[k] - mx); s += v[k]; }
            const float inv = 4.f / s;            // folds the 4*flow scale
            float o0 = 0.f, o1 = 0.f;
            #pragma unroll
            for (int ki = 0; ki < 3; ++ki)
                #pragma unroll
                for (int kj = 0; kj < 3; ++kj) {
                    const float wgt = v[ki * 3 + kj];
                    o0 += wgt * fw[0][ki][r + kj];
                    o1 += wgt * fw[1][ki][r + kj];
                }
            outs[(0 * 4 + a_) * 1028 + 4 * w + b_] = o0 * inv;
            outs[(1 * 4 + a_) * 1028 + 4 * w + b_] = o1 * inv;
        }
    }
    __syncthreads();

    // coalesced copy-out: 8192 dwords, stride-1 per 256-thread group
    const int H4 = 4 * HH, W4 = 4 * WW;
    #pragma unroll
    for (int it = 0; it < 32; ++it) {
        const int i = it * 256 + tid;
        const int w4 = i & 1023, a = (i >> 10) & 3, c = i >> 12;
        out[(((size_t)(n * 2 + c)) * H4 + 4 * h + a) * W4 + w4] =
            outs[(c * 4 + a) * 1028 + w4];
    }
}

// ---------------------------------------------------------------------------
extern "C" void kernel_launch(void* const* d_in, const int* in_sizes, int n_in,
                              void* d_out, int out_size, void* d_ws, size_t ws_size,
                              hipStream_t stream)
{
    const float* flow = (const float*)d_in[0];
    const float* feat = (const float*)d_in[1];
    const float* w1   = (const float*)d_in[2];
    const float* b1   = (const float*)d_in[3];
    const float* w2   = (const float*)d_in[4];
    const float* b2   = (const float*)d_in[5];
    float* out = (float*)d_out;

    short* featT = (short*)d_ws;
    short* hfeat = featT + (size_t)3 * NPX * 32;         // 12,582,912
    short* w1p   = hfeat + (size_t)4 * NPX * 32;         // 16,777,216
    short* w2p   = w1p + (size_t)3 * 9 * 8 * 512;        // 110,592
    short* zbuf  = w2p + (size_t)4 * 9 * 9 * 512;        // 165,888 (16B-aligned)

    const int tot1 = 3 * 9 * 8 * 512;                    // 110,592
    const int tot2 = 4 * 9 * 9 * 512;                    // 165,888

    transpose_feat<<<NN * HH, 256, 0, stream>>>(feat, featT, zbuf);
    pack_wB<<<(tot1 + 255) / 256, 256, 0, stream>>>(w1, w1p, CIN, 8, tot1);
    pack_wB<<<(tot2 + 255) / 256, 256, 0, stream>>>(w2, w2p, C1, 9, tot2);
    conv1_mfma<<<NN * HH, 256, 0, stream>>>(featT, w1p, b1, hfeat, zbuf);
    conv2_fused<<<NN * HH, 256, 0, stream>>>(hfeat, w2p, b2, flow, out, zbuf);
}

// Round 8
// 176.909 us; speedup vs baseline: 1.0254x; 1.0254x over previous
//
#include <hip/hip_runtime.h>
#include <hip/hip_bf16.h>

#define NN  4
#define CIN 96
#define C1  128
#define C2  144
#define HH  128
#define WW  256
#define NPX ((size_t)NN * HH * WW)          // pixels per chunk-plane (131072)

typedef short bf16x8 __attribute__((ext_vector_type(8)));
typedef float f32x4  __attribute__((ext_vector_type(4)));
typedef unsigned int u32x4 __attribute__((ext_vector_type(4)));

__device__ __forceinline__ short f2bs(float v) {
    __hip_bfloat16 b = __float2bfloat16(v);
    short s; __builtin_memcpy(&s, &b, 2); return s;
}

// async global->LDS, 16B per lane. LDS dest linear (base + lane*16).
__device__ __forceinline__ void gld16(const void* g, void* l) {
    __builtin_amdgcn_global_load_lds(
        (const __attribute__((address_space(1))) void*)g,
        (__attribute__((address_space(3))) void*)l, 16, 0, 0);
}

// ---------------------------------------------------------------------------
// Fused prolog: blocks [0,512) transpose feat NCHW fp32 -> chunk-major bf16
// featT[kc][n][h][w][32]; blocks [512,944) pack w1; blocks [944,1592) pack w2.
// Fewer launches = fewer serial inter-kernel gaps.
__global__ __launch_bounds__(256) void prolog(
    const float* __restrict__ feat, short* __restrict__ featT,
    short* __restrict__ zbuf,
    const float* __restrict__ w1, short* __restrict__ w1p,
    const float* __restrict__ w2, short* __restrict__ w2p)
{
    __shared__ unsigned int lds[48 * 258];        // 49.5 KB (transpose blocks only)
    const int b   = blockIdx.x;
    const int tid = threadIdx.x;

    if (b < 512) {                                // ---- transpose ----
        const int h = b & (HH - 1);
        const int n = b >> 7;
        if (b == 0 && tid < 32) zbuf[tid] = 0;

        #pragma unroll 4
        for (int cp = 0; cp < 48; ++cp) {         // channel pairs
            float v0 = feat[(((size_t)n * CIN + 2 * cp    ) * HH + h) * WW + tid];
            float v1 = feat[(((size_t)n * CIN + 2 * cp + 1) * HH + h) * WW + tid];
            unsigned int p = (unsigned int)(unsigned short)f2bs(v0)
                           | ((unsigned int)(unsigned short)f2bs(v1) << 16);
            lds[cp * 258 + tid] = p;
        }
        __syncthreads();
        const size_t rowbase = (size_t)(n * HH + h) * WW * 32;
        #pragma unroll
        for (int kc = 0; kc < 3; ++kc) {
            short* dst = featT + (size_t)kc * (NPX * 32) + rowbase;
            #pragma unroll
            for (int it = 0; it < 4; ++it) {
                const int slot = it * 256 + tid;
                const int px = slot >> 2, sub = slot & 3;
                u32x4 v;                           // ci pairs kc*16+sub*4+k
                #pragma unroll
                for (int k = 0; k < 4; ++k)
                    v[k] = lds[(kc * 16 + sub * 4 + k) * 258 + px];
                *(u32x4*)&dst[(size_t)slot * 8] = v;
            }
        }
        return;
    }

    // ---- weight packs: wp[(((kci*9+tap)*nct+ct)*64+lane)*8+j] ----
    const float* w; short* wp; int cin, nct, i;
    if (b < 944) { w = w1; wp = w1p; cin = CIN; nct = 8; i = (b - 512) * 256 + tid; }
    else         { w = w2; wp = w2p; cin = C1;  nct = 9; i = (b - 944) * 256 + tid; }
    const int j    = i & 7;
    const int col  = (i >> 3) & 15;
    const int quad = (i >> 7) & 3;
    int t = i >> 9;                               // (kci*9+tap)*nct + ct
    const int ct  = t % nct;  t /= nct;
    const int tap = t % 9;
    const int kci = t / 9;
    const int co = ct * 16 + col;
    const int ci = kci * 32 + quad * 8 + j;
    wp[i] = f2bs(w[((size_t)co * cin + ci) * 9 + tap]);
}

// ---------------------------------------------------------------------------
// conv1: r6 champion structure. 1-row blocks, 256 thr / 4 waves (wave = 64-px
// strip, mt=4), grid 512 = 2 blocks/CU (LDS 74.1 KB). A single-buffered
// (XOR-swizzled via source), B single-buffered per 3-tap group. Stage drains
// covered by the co-resident block; setprio favors MFMA-phase waves (T5).
__global__ __launch_bounds__(256, 2) void conv1_mfma(
    const short* __restrict__ featT, const short* __restrict__ w1p,
    const float* __restrict__ b1, short* __restrict__ hfeat,
    const short* __restrict__ zbuf)
{
    __shared__ __attribute__((aligned(16))) short ldsA[3 * 258 * 32];   // 49,536 B
    __shared__ __attribute__((aligned(16))) short ldsB[3 * 8 * 512];    // 24,576 B
    const int tid  = threadIdx.x;
    const int bid  = ((blockIdx.x & 7) << 6) + (blockIdx.x >> 3); // 512 = 8x64
    const int h    = bid & (HH - 1);
    const int n    = bid >> 7;
    const int lane = tid & 63, wave = tid >> 6;
    const int quad = lane >> 4, col = lane & 15;
    const int wp0  = wave * 64;

    f32x4 acc[4][8];
    #pragma unroll
    for (int mt = 0; mt < 4; ++mt)
        #pragma unroll
        for (int ct = 0; ct < 8; ++ct)
            #pragma unroll
            for (int r = 0; r < 4; ++r) acc[mt][ct][r] = 0.f;

    auto stageA = [&](int kci) {
        const short* cbase = featT + (size_t)kci * (NPX * 32);
        for (int s = tid; s < 3 * 258 * 4; s += 256) {
            const int cig = s & 3;
            const int px  = (s >> 2) % 258;
            const int row = (s >> 2) / 258;
            const int hh = h + row - 1, gw = px - 1;
            const short* g = zbuf;
            if (hh >= 0 && hh < HH && gw >= 0 && gw < WW)
                g = cbase + ((size_t)(n * HH + hh) * WW + gw) * 32
                    + ((cig ^ ((px >> 1) & 3)) << 3);   // source pre-swizzle
            gld16(g, &ldsA[s * 8]);
        }
    };
    auto stageB = [&](int kci, int tg) {
        const short* gB = w1p + (((size_t)(kci * 9 + tg * 3) * 8) << 9);
        for (int t = tid; t < 3 * 8 * 64; t += 256)     // 1536 x 16B contiguous
            gld16(gB + t * 8, &ldsB[t * 8]);
    };
    auto compute = [&](int tg) {            // tap group tg = fixed dh row
        __builtin_amdgcn_s_setprio(1);
        #pragma unroll
        for (int dw = 0; dw < 3; ++dw) {
            bf16x8 af[4];
            #pragma unroll
            for (int mt = 0; mt < 4; ++mt) {
                const int px = wp0 + mt * 16 + col + dw;
                const int slot = (tg * 258 + px) * 4 + (quad ^ ((px >> 1) & 3));
                af[mt] = *(const bf16x8*)&ldsA[slot * 8];
            }
            #pragma unroll
            for (int ct = 0; ct < 8; ++ct) {
                const bf16x8 bfr = *(const bf16x8*)&ldsB[((dw * 8 + ct) << 9) + (lane << 3)];
                #pragma unroll
                for (int mt = 0; mt < 4; ++mt)
                    acc[mt][ct] = __builtin_amdgcn_mfma_f32_16x16x32_bf16(af[mt], bfr, acc[mt][ct], 0, 0, 0);
            }
        }
        __builtin_amdgcn_s_setprio(0);
    };

    stageA(0);
    stageB(0, 0);
    __syncthreads();                              // drain (covered by co-block)
    for (int kci = 0; kci < 3; ++kci)
        for (int tg = 0; tg < 3; ++tg) {
            compute(tg);
            __syncthreads();                      // done reading A/B
            if (!(kci == 2 && tg == 2)) {
                int nk = kci, ntg = tg + 1;
                if (ntg == 3) { nk = kci + 1; ntg = 0; }
                if (ntg == 0) stageA(nk);
                stageB(nk, ntg);
                __syncthreads();                  // drain
            }
        }

    float bias[8];
    #pragma unroll
    for (int ct = 0; ct < 8; ++ct) bias[ct] = b1[ct * 16 + col];
    #pragma unroll
    for (int mt = 0; mt < 4; ++mt)
        #pragma unroll
        for (int r = 0; r < 4; ++r) {
            const int w = wp0 + mt * 16 + quad * 4 + r;
            const size_t pxw = (size_t)(n * HH + h) * WW + w;
            #pragma unroll
            for (int ct = 0; ct < 8; ++ct) {
                float a = acc[mt][ct][r] + bias[ct];
                a = a > 0.f ? a : 0.1f * a;       // LeakyReLU(0.1)
                hfeat[((size_t)(ct >> 1) * NPX + pxw) * 32 + (ct & 1) * 16 + col] = f2bs(a);
            }
        }
}

// ---------------------------------------------------------------------------
// conv2 + fused epilogue. r6 champion structure (4 K-chunks x 3 tap-groups,
// nct=9, LDS 77.2 KB -> 2 blocks/CU) + setprio around MFMA clusters.
// Epilogue: LDS out-stage (stride 1028) -> fully coalesced copy-out.
__global__ __launch_bounds__(256, 2) void conv2_fused(
    const short* __restrict__ hfeat, const short* __restrict__ w2p,
    const float* __restrict__ b2, const float* __restrict__ flow,
    float* __restrict__ out, const short* __restrict__ zbuf)
{
    __shared__ __attribute__((aligned(16))) short ldsA[3 * 258 * 32];   // 49,536 B
    __shared__ __attribute__((aligned(16))) short ldsB[3 * 9 * 512];    // 27,648 B
    const int tid  = threadIdx.x;
    const int bid  = ((blockIdx.x & 7) << 6) + (blockIdx.x >> 3);
    const int h    = bid & (HH - 1);
    const int n    = bid >> 7;
    const int lane = tid & 63, wave = tid >> 6;
    const int quad = lane >> 4, col = lane & 15;
    const int wp0  = wave * 64;

    f32x4 acc[4][9];
    #pragma unroll
    for (int mt = 0; mt < 4; ++mt)
        #pragma unroll
        for (int ct = 0; ct < 9; ++ct)
            #pragma unroll
            for (int r = 0; r < 4; ++r) acc[mt][ct][r] = 0.f;

    auto stageA = [&](int kci) {
        const short* cbase = hfeat + (size_t)kci * (NPX * 32);
        for (int s = tid; s < 3 * 258 * 4; s += 256) {
            const int cig = s & 3;
            const int px  = (s >> 2) % 258;
            const int row = (s >> 2) / 258;
            const int hh = h + row - 1, gw = px - 1;
            const short* g = zbuf;
            if (hh >= 0 && hh < HH && gw >= 0 && gw < WW)
                g = cbase + ((size_t)(n * HH + hh) * WW + gw) * 32
                    + ((cig ^ ((px >> 1) & 3)) << 3);
            gld16(g, &ldsA[s * 8]);
        }
    };
    auto stageB = [&](int kci, int tg) {
        const short* gB = w2p + (((size_t)(kci * 9 + tg * 3) * 9) << 9);
        for (int t = tid; t < 3 * 9 * 64; t += 256)     // 1728 x 16B contiguous
            gld16(gB + t * 8, &ldsB[t * 8]);
    };
    auto compute = [&](int tg) {
        __builtin_amdgcn_s_setprio(1);
        #pragma unroll
        for (int dw = 0; dw < 3; ++dw) {
            bf16x8 af[4];
            #pragma unroll
            for (int mt = 0; mt < 4; ++mt) {
                const int px = wp0 + mt * 16 + col + dw;
                const int slot = (tg * 258 + px) * 4 + (quad ^ ((px >> 1) & 3));
                af[mt] = *(const bf16x8*)&ldsA[slot * 8];
            }
            #pragma unroll
            for (int ct = 0; ct < 9; ++ct) {
                const bf16x8 bfr = *(const bf16x8*)&ldsB[((dw * 9 + ct) << 9) + (lane << 3)];
                #pragma unroll
                for (int mt = 0; mt < 4; ++mt)
                    acc[mt][ct] = __builtin_amdgcn_mfma_f32_16x16x32_bf16(af[mt], bfr, acc[mt][ct], 0, 0, 0);
            }
        }
        __builtin_amdgcn_s_setprio(0);
    };

    stageA(0);
    stageB(0, 0);
    __syncthreads();
    for (int kci = 0; kci < 4; ++kci)
        for (int tg = 0; tg < 3; ++tg) {
            compute(tg);
            __syncthreads();
            if (!(kci == 3 && tg == 2)) {
                int nk = kci, ntg = tg + 1;
                if (ntg == 3) { nk = kci + 1; ntg = 0; }
                if (ntg == 0) stageA(nk);
                stageB(nk, ntg);
                __syncthreads();
            }
        }

    // ---- epilogue: ldsA reused as out-stage [2][4][1028] + flow cache ----
    float* outs = (float*)ldsA;                   // 32,896 B
    float* flds = (float*)ldsA + 8224;            // [2][3][264], 6,336 B
    for (int i = tid; i < 2 * 3 * 258; i += 256) {
        const int px = i % 258;
        const int t  = i / 258;
        const int row = t % 3, c = t / 3;
        const int hh = h + row - 1, gw = px - 1;
        float v = 0.f;
        if (hh >= 0 && hh < HH && gw >= 0 && gw < WW)
            v = flow[(((size_t)n * 2 + c) * HH + hh) * WW + gw];
        flds[(c * 3 + row) * 264 + px] = v;
    }
    __syncthreads();

    const int a_ = col >> 2, b_ = col & 3;
    float bias[9];
    #pragma unroll
    for (int k = 0; k < 9; ++k) bias[k] = b2[k * 16 + col];

    #pragma unroll
    for (int mt = 0; mt < 4; ++mt) {
        const int w0 = wp0 + mt * 16 + quad * 4;
        float fw[2][3][6];                        // flow window w0-1 .. w0+4
        #pragma unroll
        for (int c = 0; c < 2; ++c)
            #pragma unroll
            for (int ki = 0; ki < 3; ++ki)
                #pragma unroll
                for (int j = 0; j < 6; ++j)
                    fw[c][ki][j] = flds[(c * 3 + ki) * 264 + w0 + j];
        #pragma unroll
        for (int r = 0; r < 4; ++r) {
            const int w = w0 + r;
            float v[9], mx = -1e30f;
            #pragma unroll
            for (int k = 0; k < 9; ++k) {
                v[k] = 0.25f * (acc[mt][k][r] + bias[k]);
                mx = fmaxf(mx, v[k]);
            }
            float s = 0.f;
            #pragma unroll
            for (int k = 0; k < 9; ++k) { v[k] = __expf(v[k] - mx); s += v[k]; }
            const float inv = 4.f / s;            // folds the 4*flow scale
            float o0 = 0.f, o1 = 0.f;
            #pragma unroll
            for (int ki = 0; ki < 3; ++ki)
                #pragma unroll
                for (int kj = 0; kj < 3; ++kj) {
                    const float wgt = v[ki * 3 + kj];
                    o0 += wgt * fw[0][ki][r + kj];
                    o1 += wgt * fw[1][ki][r + kj];
                }
            outs[(0 * 4 + a_) * 1028 + 4 * w + b_] = o0 * inv;
            outs[(1 * 4 + a_) * 1028 + 4 * w + b_] = o1 * inv;
        }
    }
    __syncthreads();

    // coalesced copy-out: 8192 dwords, stride-1 per 256-thread group
    const int H4 = 4 * HH, W4 = 4 * WW;
    #pragma unroll
    for (int it = 0; it < 32; ++it) {
        const int i = it * 256 + tid;
        const int w4 = i & 1023, a = (i >> 10) & 3, c = i >> 12;
        out[(((size_t)(n * 2 + c)) * H4 + 4 * h + a) * W4 + w4] =
            outs[(c * 4 + a) * 1028 + w4];
    }
}

// ---------------------------------------------------------------------------
extern "C" void kernel_launch(void* const* d_in, const int* in_sizes, int n_in,
                              void* d_out, int out_size, void* d_ws, size_t ws_size,
                              hipStream_t stream)
{
    const float* flow = (const float*)d_in[0];
    const float* feat = (const float*)d_in[1];
    const float* w1   = (const float*)d_in[2];
    const float* b1   = (const float*)d_in[3];
    const float* w2   = (const float*)d_in[4];
    const float* b2   = (const float*)d_in[5];
    float* out = (float*)d_out;

    short* featT = (short*)d_ws;
    short* hfeat = featT + (size_t)3 * NPX * 32;         // 12,582,912
    short* w1p   = hfeat + (size_t)4 * NPX * 32;         // 16,777,216
    short* w2p   = w1p + (size_t)3 * 9 * 8 * 512;        // 110,592
    short* zbuf  = w2p + (size_t)4 * 9 * 9 * 512;        // 165,888 (16B-aligned)

    // blocks: 512 transpose + 432 pack-w1 + 648 pack-w2 = 1592
    prolog<<<1592, 256, 0, stream>>>(feat, featT, zbuf, w1, w1p, w2, w2p);
    conv1_mfma<<<NN * HH, 256, 0, stream>>>(featT, w1p, b1, hfeat, zbuf);
    conv2_fused<<<NN * HH, 256, 0, stream>>>(hfeat, w2p, b2, flow, out, zbuf);
}